// Round 10
// baseline (607.536 us; speedup 1.0000x reference)
//
#include <hip/hip_runtime.h>

typedef unsigned short u16;
typedef unsigned int u32;
typedef __bf16 bf16_t;
typedef bf16_t bf16x8 __attribute__((ext_vector_type(8)));
typedef float f32x4 __attribute__((ext_vector_type(4)));
typedef u16 u16x8 __attribute__((ext_vector_type(8)));
typedef u16 u16x4 __attribute__((ext_vector_type(4)));

__device__ __forceinline__ u16 f2bf(float f) {
    u32 u = __float_as_uint(f);
    u32 r = u + 0x7fffu + ((u >> 16) & 1u);   // RNE
    return (u16)(r >> 16);
}

// async global->LDS, 16B per lane. LDS dest = wave-uniform base + lane*16.
__device__ __forceinline__ void async16(const void* g, void* l) {
    __builtin_amdgcn_global_load_lds(
        (__attribute__((address_space(1))) u32*)g,
        (__attribute__((address_space(3))) u32*)l,
        16, 0, 0);
}

// ---------------------------------------------------------------- convert
__global__ void cvt_bf16(const float* __restrict__ in, u16* __restrict__ out, int n) {
    for (int i = (blockIdx.x * blockDim.x + threadIdx.x) * 4; i < n;
         i += gridDim.x * blockDim.x * 4) {
        const float4 f = *reinterpret_cast<const float4*>(in + i);
        u16x4 uu = {f2bf(f.x), f2bf(f.y), f2bf(f.z), f2bf(f.w)};
        *reinterpret_cast<u16x4*>(out + i) = uu;
    }
}

// ---------------------------------------------------------------- GEMM: C = A * Bt^T + bias
// A [M,K] bf16 row-major, Bt [N,K] bf16 row-major (torch Linear weight), bias fp32 [N]
constexpr int BM = 128, BN = 128, BK = 32;

template <bool OUT_BF16>
__global__ __launch_bounds__(256, 2)
void gemm_bt(const u16* __restrict__ A, const u16* __restrict__ Bt,
             const float* __restrict__ bias, void* __restrict__ Cout,
             int M, int N, int K)
{
    __shared__ u16 As[2][BM * BK];
    __shared__ u16 Bs[2][BN * BK];
    const int tid = threadIdx.x;
    const int w  = tid >> 6;
    const int l  = tid & 63;
    const int l4 = l & 15;        // row within 16x16 fragment
    const int lk = l >> 4;        // k-chunk (8 bf16 each)
    const int m0 = blockIdx.y * BM;
    const int n0 = blockIdx.x * BN;
    const int wr = (w >> 1) * 64;
    const int wc = (w & 1) * 64;
    const int NK = K / BK;

    f32x4 acc[4][4];
#pragma unroll
    for (int m = 0; m < 4; ++m)
#pragma unroll
        for (int n = 0; n < 4; ++n)
            acc[m][n] = f32x4{0.f, 0.f, 0.f, 0.f};

    const int srow = l >> 2;          // 0..15 : row within 16-row stage chunk
    const int scol = (l & 3) * 8;     // elem offset within 32-elem row

    auto stage = [&](int buf, int kt) {
        const int k0 = kt * BK;
#pragma unroll
        for (int i = 0; i < 2; ++i) {
            const int r0 = (w * 2 + i) * 16;   // 16 rows per instr, wave covers 32
            async16(A + (size_t)(m0 + r0 + srow) * K + k0 + scol, &As[buf][r0 * BK]);
            async16(Bt + (size_t)(n0 + r0 + srow) * K + k0 + scol, &Bs[buf][r0 * BK]);
        }
    };

    stage(0, 0);
    int cur = 0;
    for (int kt = 0; kt < NK; ++kt) {
        __syncthreads();                       // drains staging vmcnt + lds reads
        if (kt + 1 < NK) stage(cur ^ 1, kt + 1);
        const u16* as = As[cur];
        const u16* bs = Bs[cur];
        bf16x8 af[4], bfg[4];
#pragma unroll
        for (int m = 0; m < 4; ++m)
            af[m] = *reinterpret_cast<const bf16x8*>(as + (wr + m * 16 + l4) * BK + lk * 8);
#pragma unroll
        for (int n = 0; n < 4; ++n)
            bfg[n] = *reinterpret_cast<const bf16x8*>(bs + (wc + n * 16 + l4) * BK + lk * 8);
#pragma unroll
        for (int m = 0; m < 4; ++m)
#pragma unroll
            for (int n = 0; n < 4; ++n)
                acc[m][n] = __builtin_amdgcn_mfma_f32_16x16x32_bf16(af[m], bfg[n], acc[m][n], 0, 0, 0);
        cur ^= 1;
    }

    // epilogue: bias + store.  D layout: col = l&15, row = (l>>4)*4 + r
#pragma unroll
    for (int n = 0; n < 4; ++n) {
        const int col = n0 + wc + n * 16 + l4;
        const float bv = bias[col];
#pragma unroll
        for (int m = 0; m < 4; ++m) {
            const int row = m0 + wr + m * 16 + lk * 4;
#pragma unroll
            for (int r = 0; r < 4; ++r) {
                const float vv = acc[m][n][r] + bv;
                if constexpr (OUT_BF16)
                    ((u16*)Cout)[(size_t)(row + r) * N + col] = f2bf(vv);
                else
                    ((float*)Cout)[(size_t)(row + r) * N + col] = vv;
            }
        }
    }
}

// ---------------------------------------------------------------- flash attention
// q [B*S, E] bf16 ; k,v [B*S, 512] bf16 ; o [B*S, E] bf16
__global__ __launch_bounds__(256, 2)
void gqa_attn(const u16* __restrict__ q, const u16* __restrict__ k,
              const u16* __restrict__ v, u16* __restrict__ o)
{
    constexpr int S = 2048, E = 2048, KVW = 512, D = 64, QT = 128, KT = 64;
    // Row stride 72 u16 = 144B: multiple of 16B (ds_read_b128 alignment kept)
    // and 36 dwords ≡ 4 mod 32 -> b128 reads hit the 8-dword/bank floor.
    constexpr int VSTR = 72;
    constexpr int PSTR = 72;
    constexpr float SCALE = 0.125f;                   // 1/sqrt(64)
    constexpr float L2E = 1.4426950408889634f;

    __shared__ u16 Ks[KT * D];        // [t][d] 64x64 (gload_lds dest: MUST stay linear)
    __shared__ u16 Vt[D * VSTR];      // [d][t] padded (PV B-operand)
    __shared__ u16 Ps[4][32 * PSTR];  // per-wave P round-trip, padded

    const int tid = threadIdx.x;
    const int w  = tid >> 6;
    const int l  = tid & 63;
    const int l4 = l & 15;
    const int lk = l >> 4;

    const int qt = blockIdx.x;      // 0..15
    const int bh = blockIdx.y;      // 0..63
    const int b  = bh >> 5;
    const int h  = bh & 31;
    const int g  = h >> 2;          // GH = 4

    const size_t qbase = ((size_t)(b * S + qt * QT)) * E + h * D;
    const size_t kvb   = (size_t)b * S * KVW + g * D;

    // Q fragments in registers (A-operand layout: row = l&15, k = (l>>4)*8 ..)
    bf16x8 qf[2][2];
#pragma unroll
    for (int m = 0; m < 2; ++m)
#pragma unroll
        for (int c = 0; c < 2; ++c)
            qf[m][c] = *reinterpret_cast<const bf16x8*>(
                q + qbase + (size_t)(w * 32 + m * 16 + l4) * E + c * 32 + lk * 8);

    f32x4 of[2][4];
    float mst[2][4], ssum[2][4];
#pragma unroll
    for (int m = 0; m < 2; ++m) {
#pragma unroll
        for (int nd = 0; nd < 4; ++nd) of[m][nd] = f32x4{0.f, 0.f, 0.f, 0.f};
#pragma unroll
        for (int r = 0; r < 4; ++r) { mst[m][r] = -1e30f; ssum[m][r] = 0.f; }
    }

    for (int kv = 0; kv < S / KT; ++kv) {
        const int t0 = kv * KT;
        // stage K tile [64][64] via global_load_lds (8 rows / instr)
#pragma unroll
        for (int i = 0; i < 2; ++i) {
            const int r0 = (w * 2 + i) * 8;
            async16(k + kvb + (size_t)(t0 + r0 + (l >> 3)) * KVW + (l & 7) * 8,
                    &Ks[r0 * D]);
        }
        // stage V transposed: thread reads 8 contiguous d, scatters into Vt[d][t]
#pragma unroll
        for (int i = 0; i < 2; ++i) {
            const int c  = tid + i * 256;       // 0..511
            const int tr = c >> 3, dc = c & 7;
            u16x8 raw = *reinterpret_cast<const u16x8*>(
                v + kvb + (size_t)(t0 + tr) * KVW + dc * 8);
#pragma unroll
            for (int e = 0; e < 8; ++e)
                Vt[(dc * 8 + e) * VSTR + tr] = raw[e];
        }
        __syncthreads();

        // S = Q K^T  (B-operand: B[k=d][j=t] = K[t][d] -> rows of Ks)
        f32x4 sf[2][4];
#pragma unroll
        for (int m = 0; m < 2; ++m)
#pragma unroll
            for (int n = 0; n < 4; ++n) sf[m][n] = f32x4{0.f, 0.f, 0.f, 0.f};
#pragma unroll
        for (int c = 0; c < 2; ++c) {
            bf16x8 kf[4];
#pragma unroll
            for (int n = 0; n < 4; ++n)
                kf[n] = *reinterpret_cast<const bf16x8*>(&Ks[(n * 16 + l4) * D + c * 32 + lk * 8]);
#pragma unroll
            for (int m = 0; m < 2; ++m)
#pragma unroll
                for (int n = 0; n < 4; ++n)
                    sf[m][n] = __builtin_amdgcn_mfma_f32_16x16x32_bf16(qf[m][c], kf[n], sf[m][n], 0, 0, 0);
        }

        // online softmax (per q-row; lane holds rows lk*4+r, cols l4 (+16n))
#pragma unroll
        for (int m = 0; m < 2; ++m) {
            float tm[4] = {-1e30f, -1e30f, -1e30f, -1e30f};
#pragma unroll
            for (int n = 0; n < 4; ++n)
#pragma unroll
                for (int r = 0; r < 4; ++r) {
                    sf[m][n][r] *= SCALE;
                    tm[r] = fmaxf(tm[r], sf[m][n][r]);
                }
#pragma unroll
            for (int off = 1; off < 16; off <<= 1)
#pragma unroll
                for (int r = 0; r < 4; ++r)
                    tm[r] = fmaxf(tm[r], __shfl_xor(tm[r], off));
            float corr[4];
#pragma unroll
            for (int r = 0; r < 4; ++r) {
                const float mn = fmaxf(mst[m][r], tm[r]);
                corr[r] = exp2f((mst[m][r] - mn) * L2E);
                mst[m][r] = mn;
            }
            float ps[4] = {0.f, 0.f, 0.f, 0.f};
#pragma unroll
            for (int n = 0; n < 4; ++n)
#pragma unroll
                for (int r = 0; r < 4; ++r) {
                    const float p = exp2f((sf[m][n][r] - mst[m][r]) * L2E);
                    sf[m][n][r] = p;
                    ps[r] += p;
                }
#pragma unroll
            for (int off = 1; off < 16; off <<= 1)
#pragma unroll
                for (int r = 0; r < 4; ++r)
                    ps[r] += __shfl_xor(ps[r], off);
#pragma unroll
            for (int r = 0; r < 4; ++r)
                ssum[m][r] = ssum[m][r] * corr[r] + ps[r];
#pragma unroll
            for (int nd = 0; nd < 4; ++nd)
#pragma unroll
                for (int r = 0; r < 4; ++r)
                    of[m][nd][r] *= corr[r];
            // write P (bf16) to per-wave LDS for A-operand re-layout
#pragma unroll
            for (int n = 0; n < 4; ++n)
#pragma unroll
                for (int r = 0; r < 4; ++r)
                    Ps[w][(m * 16 + lk * 4 + r) * PSTR + n * 16 + l4] = f2bf(sf[m][n][r]);
        }
        // NOTE: no __syncthreads() here. Ps is PER-WAVE (Ps[w]); DS ops from
        // one wave complete in issue order, so the wave's own PV reads below
        // see its writes without a block barrier. Vt/Ks reads are still
        // protected by the post-staging barrier above; the end-of-loop
        // barrier protects next iteration's overwrite.

        // O += P V   (A = P rows, B[k=t][j=d] = Vt[d][t] rows)
#pragma unroll
        for (int c = 0; c < 2; ++c) {
            bf16x8 pa[2], vf[4];
#pragma unroll
            for (int m = 0; m < 2; ++m)
                pa[m] = *reinterpret_cast<const bf16x8*>(&Ps[w][(m * 16 + l4) * PSTR + c * 32 + lk * 8]);
#pragma unroll
            for (int nd = 0; nd < 4; ++nd)
                vf[nd] = *reinterpret_cast<const bf16x8*>(&Vt[(nd * 16 + l4) * VSTR + c * 32 + lk * 8]);
#pragma unroll
            for (int m = 0; m < 2; ++m)
#pragma unroll
                for (int nd = 0; nd < 4; ++nd)
                    of[m][nd] = __builtin_amdgcn_mfma_f32_16x16x32_bf16(pa[m], vf[nd], of[m][nd], 0, 0, 0);
        }
        __syncthreads();
    }

    // finalize: divide by softmax sum, store bf16
#pragma unroll
    for (int m = 0; m < 2; ++m)
#pragma unroll
        for (int nd = 0; nd < 4; ++nd) {
            const int col = nd * 16 + l4;
#pragma unroll
            for (int r = 0; r < 4; ++r) {
                const int row = qt * QT + w * 32 + m * 16 + lk * 4 + r;
                const float val = of[m][nd][r] / ssum[m][r];
                o[((size_t)(b * S + row)) * E + h * D + col] = f2bf(val);
            }
        }
}

// ---------------------------------------------------------------- launch
extern "C" void kernel_launch(void* const* d_in, const int* in_sizes, int n_in,
                              void* d_out, int out_size, void* d_ws, size_t ws_size,
                              hipStream_t stream)
{
    constexpr int E = 2048, KVW = 512;
    const float* x  = (const float*)d_in[0];
    const float* Wq = (const float*)d_in[1];
    const float* bq = (const float*)d_in[2];
    const float* Wk = (const float*)d_in[3];
    const float* bk = (const float*)d_in[4];
    const float* Wv = (const float*)d_in[5];
    const float* bv = (const float*)d_in[6];
    const float* Wo = (const float*)d_in[7];
    const float* bo = (const float*)d_in[8];
    const int M = in_sizes[0] / E;    // B*S = 4096

    // Workspace layout (aliased to keep footprint ~55 MB):
    //   xb  [M*E]   : x in bf16; dead after the 3 projection GEMMs
    //   wqb [E*E]   : Wq bf16; dead after Q-GEMM -> reused for Wo bf16
    //   ob          : attention output; aliases xb (stream order makes this safe)
    u16* ws = (u16*)d_ws;
    size_t off = 0;
    u16* xb  = ws + off; off += (size_t)M * E;
    u16* wqb = ws + off; off += (size_t)E * E;
    u16* wkb = ws + off; off += (size_t)KVW * E;
    u16* wvb = ws + off; off += (size_t)KVW * E;
    u16* qb  = ws + off; off += (size_t)M * E;
    u16* kb  = ws + off; off += (size_t)M * KVW;
    u16* vb  = ws + off; off += (size_t)M * KVW;
    u16* ob  = xb;       // alias: x-bf16 dead once projections are done
    u16* wob = wqb;      // alias: Wq-bf16 dead once Q-GEMM is done

    cvt_bf16<<<512, 256, 0, stream>>>(x,  xb,  M * E);
    cvt_bf16<<<512, 256, 0, stream>>>(Wq, wqb, E * E);
    cvt_bf16<<<512, 256, 0, stream>>>(Wk, wkb, KVW * E);
    cvt_bf16<<<512, 256, 0, stream>>>(Wv, wvb, KVW * E);

    gemm_bt<true><<<dim3(E / BN,   M / BM), 256, 0, stream>>>(xb, wqb, bq, qb, M, E,   E);
    gemm_bt<true><<<dim3(KVW / BN, M / BM), 256, 0, stream>>>(xb, wkb, bk, kb, M, KVW, E);
    gemm_bt<true><<<dim3(KVW / BN, M / BM), 256, 0, stream>>>(xb, wvb, bv, vb, M, KVW, E);

    // Wo convert deferred until wqb is dead (Q-GEMM retired before this point
    // in stream order; conversion kernel only needs to precede the final GEMM)
    cvt_bf16<<<512, 256, 0, stream>>>(Wo, wob, E * E);

    gqa_attn<<<dim3(16, 64), 256, 0, stream>>>(qb, kb, vb, ob);

    gemm_bt<false><<<dim3(E / BN, M / BM), 256, 0, stream>>>(ob, wob, bo, (float*)d_out, M, E, E);
}